// Round 5
// baseline (125.804 us; speedup 1.0000x reference)
//
#include <hip/hip_runtime.h>

constexpr int NIN = 96, NOUT = 192;
constexpr int TZ = 2, TY = 4;              // input tile (z,y), full x
constexpr int HZ = TZ + 1, HY = TY + 1;    // 3, 5 (with +1 halo)
constexpr int ROWS = HZ * HY;              // 15 staged rows
constexpr int HXP = 98;                    // padded row length in float2 (784 B, 16B-aligned)
constexpr int F4R = NIN / 2;               // 48 float4 per input row
constexpr int NTZ = NIN / TZ, NTY = NIN / TY;  // 48, 24

typedef float vfloat4 __attribute__((ext_vector_type(4)));   // native vector: ok for nontemporal builtin

__global__ __launch_bounds__(192) void resize_zoom2_v4(
        const float* __restrict__ in, float* __restrict__ out) {
    __shared__ __align__(16) float2 S[ROWS * HXP];   // 11760 B

    const int bid = blockIdx.x;
    const int yt = bid % NTY;
    const int tt = bid / NTY;
    const int zt = tt % NTZ;
    const int b  = tt / NTZ;
    const int z0 = zt * TZ, y0 = yt * TY;

    const float* vb = in + (size_t)b * ((size_t)NIN * NIN * NIN * 2);
    const float4* vin4 = (const float4*)vb;

    // ---- stage 15 halo'd rows (clamped), float4-vectorized, coalesced
    for (int i = threadIdx.x; i < ROWS * F4R; i += 192) {
        int r = i / F4R, col = i - r * F4R;
        int zi = min(z0 + r / HY, NIN - 1);
        int yi = min(y0 + (r - (r / HY) * HY), NIN - 1);
        float4 v = vin4[(size_t)(zi * NIN + yi) * F4R + col];
        *(float4*)((float*)(S + r * HXP) + 4 * col) = v;
    }
    if (threadIdx.x < ROWS) {               // x halo element (clamp of x=96)
        int r = threadIdx.x;
        int zi = min(z0 + r / HY, NIN - 1);
        int yi = min(y0 + r % HY, NIN - 1);
        S[r * HXP + NIN] = ((const float2*)vb)[(size_t)(zi * NIN + yi) * NIN + (NIN - 1)];
    }
    __syncthreads();

    // ---- compute: thread owns fixed (yhalf, xp); rolls along z carrying plane sums
    const int xp = threadIdx.x % NIN;       // 0..95  (output x-pair)
    const int yh = threadIdx.x / NIN;       // 0..1
    vfloat4* vout = (vfloat4*)out;
    constexpr size_t ZSTR = (size_t)NOUT * (NOUT / 2);   // float4 per output z-plane
    size_t ob = ((size_t)(b * NOUT + 2 * z0) * NOUT + (2 * y0 + yh)) * (NOUT / 2) + xp;

    #pragma unroll
    for (int y2 = 0; y2 < TY; ++y2) {
        const int yo = 2 * y2 + yh;
        const int yA = yo >> 1, yB = yA + (yo & 1);
        const float2* pA = S + yA * HXP;    // plane stride = HY*HXP
        const float2* pB = S + yB * HXP;

        float2 aA = pA[xp],     aB = pB[xp];
        float2 cA = pA[xp + 1], cB = pB[xp + 1];
        float sy_x  = aA.x + aB.x, sy_y  = aA.y + aB.y;   // plane-k y-sum at x
        float syc_x = cA.x + cB.x, syc_y = cA.y + cB.y;   // plane-k y-sum at x+1
        size_t o = ob + (size_t)y2 * NOUT;  // +2 output rows per y2

        #pragma unroll
        for (int k = 0; k < TZ; ++k) {
            const float2* qA = pA + (k + 1) * HY * HXP;
            const float2* qB = pB + (k + 1) * HY * HXP;
            float2 bA = qA[xp],     bB = qB[xp];
            float2 dA = qA[xp + 1], dB = qB[xp + 1];
            float ty_x  = bA.x + bB.x, ty_y  = bA.y + bB.y;  // plane-(k+1) sums
            float tyc_x = dA.x + dB.x, tyc_y = dA.y + dB.y;

            // zo = 2k (even z): plane k only — stream past L2 (write-once data)
            vfloat4 v_even = {0.5f * sy_x, 0.5f * sy_y,
                              0.25f * (sy_x + syc_x), 0.25f * (sy_y + syc_y)};
            __builtin_nontemporal_store(v_even, &vout[o + (size_t)(2 * k) * ZSTR]);

            // zo = 2k+1 (odd z): planes k and k+1
            float ux = sy_x + ty_x, uy = sy_y + ty_y;
            float vx = ux + syc_x + tyc_x, vy = uy + syc_y + tyc_y;
            vfloat4 v_odd = {0.25f * ux, 0.25f * uy, 0.125f * vx, 0.125f * vy};
            __builtin_nontemporal_store(v_odd, &vout[o + (size_t)(2 * k + 1) * ZSTR]);

            sy_x = ty_x; sy_y = ty_y; syc_x = tyc_x; syc_y = tyc_y;
        }
    }
}

extern "C" void kernel_launch(void* const* d_in, const int* in_sizes, int n_in,
                              void* d_out, int out_size, void* d_ws, size_t ws_size,
                              hipStream_t stream) {
    const float* in = (const float*)d_in[0];
    float* out = (float*)d_out;
    const int grid = 2 * NTZ * NTY;   // 2304 blocks
    resize_zoom2_v4<<<grid, 192, 0, stream>>>(in, out);
}